// Round 5
// baseline (1223.112 us; speedup 1.0000x reference)
//
#include <hip/hip_runtime.h>
#include <hip/hip_bf16.h>

// LIF fused kernel, Round 8: register-expanded A + 2 independent blocks/CU.
//
// R7 post-mortem: 2 lockstep waves/SIMD gave only 1.21x (575us, MfmaUtil 30%).
// Same-block waves are co-phased by the barrier -> VALU/MFMA/LDS pile up in
// the same window; no bubble-filling. SQ_LDS_BANK_CONFLICT constant 2^25
// across all rounds = saturated artifact, ignore.
//
// R8 structure:
//  - A-fragments built IN REGISTERS from the bit-packed spikes: per t each
//    lane loads uintx2 (its 64 frag bits) and expands bits->bf16 via exact
//    shift-sub (x*0x3F80 = (x<<14)-(x<<7)). No LDS for A at all; barrier
//    only orders the small xbuf partial buffer.
//  - Grid 512 = 16 b-tiles x 32 g-tiles, block 512 thr = 8 waves = 8
//    K-eighths (wq). launch_bounds(512,4): 2 blocks/CU -> 4 waves/SIMD from
//    INDEPENDENT barrier domains (real phase diversity).
//  - Double-buffered xbuf (7 partials), deferred LIF on wq0, one barrier/t.
//  - MFMA ks=0 uses C=0 const regs (no per-t accumulator zeroing).
// Numerics: A/W values and MFMA order identical to R7; K-reduction is now
// 8-way sequential (own+p0..p6) -> absmax expected ~0.004-0.008.
//
// Packed layout: bits[t*4096 + b*16 + wd], bit j (LSB) = spike[t][b][wd*32+j].

typedef __attribute__((ext_vector_type(8))) short short8;   // 8 x bf16
typedef __attribute__((ext_vector_type(4))) float floatx4;
typedef __attribute__((ext_vector_type(2))) unsigned uintx2;
typedef __attribute__((ext_vector_type(4))) unsigned uintx4;

#define T_STEPS 1024
#define B_DIM   256
#define F_DIM   512
#define BF      (B_DIM * F_DIM)
#define ROWP    520   // (fallback kernel only)

static __device__ __forceinline__ unsigned short f2bf_rne(float f) {
    unsigned u = __float_as_uint(f);
    return (unsigned short)((u + 0x7FFFu + ((u >> 16) & 1u)) >> 16);
}
static __device__ __forceinline__ float bf2f(unsigned short h) {
    return __uint_as_float(((unsigned)h) << 16);
}

// ---------------- prepass: fp32 {0,1} -> bitmask ----------------
__global__ __launch_bounds__(256)
void pack_kernel(const float* __restrict__ sp, unsigned* __restrict__ bits)
{
    const int lane = threadIdx.x & 63;
    const int wv   = blockIdx.x * 4 + (threadIdx.x >> 6);
    for (int c = wv; c < 65536; c += 2048 * 4) {
        const float* p = sp + (size_t)c * 2048;
        unsigned val = 0;
        #pragma unroll
        for (int r = 0; r < 32; ++r) {
            float x = p[r * 64 + lane];
            unsigned long long m = __ballot(x != 0.0f);
            unsigned sel = (lane & 1) ? (unsigned)(m >> 32) : (unsigned)m;
            if ((lane >> 1) == r) val = sel;
        }
        bits[(size_t)c * 64 + lane] = val;
    }
}

// -------- main kernel: register A, 8 K-eighth waves, 2 blocks/CU --------
__global__ __launch_bounds__(512, 4)
void lif_kernel_bits(const unsigned* __restrict__ bits,
                     const float* __restrict__ W,
                     float* __restrict__ out)
{
    __shared__ float xbuf[2][7 * 256];   // dbuf x 7 partial waves x 16x16 tile

    const int tid  = threadIdx.x;
    const int lane = tid & 63;
    const int wq   = tid >> 6;          // 0..7: K-eighth, k in [wq*64, wq*64+64)
    const int bt   = blockIdx.x & 15;
    const int gb   = blockIdx.x >> 4;   // 0..31
    const int b0   = bt * 16;
    const int gw   = gb * 16;
    const int mrow = lane & 15;
    const int lq   = lane >> 4;         // 0..3
    const int bsh  = lq * 8;            // byte shift within bits dword

    // ---- W fragments (once): rows gw+mrow, k = wq*64 + ks*32 + lq*8 + j
    short8 whi[2], wmd[2], wlo[2];
    {
        const float* wp = W + (size_t)(gw + mrow) * F_DIM + wq * 64 + lq * 8;
        #pragma unroll
        for (int ks = 0; ks < 2; ++ks) {
            short8 hi, md, lo;
            #pragma unroll
            for (int j = 0; j < 8; ++j) {
                float f = wp[ks * 32 + j];
                unsigned short h = f2bf_rne(f);
                float r1 = f - bf2f(h);
                unsigned short m = f2bf_rne(r1);
                float r2 = r1 - bf2f(m);
                hi[j] = (short)h;
                md[j] = (short)m;
                lo[j] = (short)f2bf_rne(r2);
            }
            whi[ks] = hi; wmd[ks] = md; wlo[ks] = lo;
        }
    }

    // ---- LIF state (wq==0 wave), C-layout: b = b0+lq*4+r, g = gw+mrow
    float v[4]  = {0.f, 0.f, 0.f, 0.f};
    float cu[4] = {0.f, 0.f, 0.f, 0.f};
    float zf[4] = {0.f, 0.f, 0.f, 0.f};

    // bits source: lane needs words wq*2, wq*2+1 of row b0+mrow (8B, aligned)
    const unsigned* bp = bits + (size_t)(b0 + mrow) * 16 + wq * 2;  // +4096/t

    auto ldbits = [&](int t) -> uintx2 {
        return *(const uintx2*)(bp + (size_t)t * 4096);
    };

    // expand 2x32 bits -> 2 x short8 A-frags (elements k = wq*64+ks*32+lq*8+j)
    // per dword pair: x = (u>>2q)&0x10001; d = (x<<14)-(x<<7)  (== x*0x3F80)
    auto expand = [&](uintx2 bq, short8* af) {
        #pragma unroll
        for (int ks = 0; ks < 2; ++ks) {
            unsigned b8 = (bq[ks] >> bsh) & 0xFFu;
            unsigned u  = b8 | (b8 << 15);
            unsigned x0 =  u        & 0x10001u;
            unsigned x1 = (u >> 2)  & 0x10001u;
            unsigned x2 = (u >> 4)  & 0x10001u;
            unsigned x3 = (u >> 6)  & 0x10001u;
            uintx4 d;
            d[0] = (x0 << 14) - (x0 << 7);
            d[1] = (x1 << 14) - (x1 << 7);
            d[2] = (x2 << 14) - (x2 << 7);
            d[3] = (x3 << 14) - (x3 << 7);
            af[ks] = *(short8*)&d;
        }
    };

    const floatx4 fz = {0.f, 0.f, 0.f, 0.f};

    // 6 MFMA; ks=0 consumes C=0 (no per-t accumulator zeroing)
    auto mfma3 = [&](const short8* af, floatx4& ah, floatx4& am, floatx4& al) {
        ah = __builtin_amdgcn_mfma_f32_16x16x32_bf16(af[0], whi[0], fz, 0, 0, 0);
        am = __builtin_amdgcn_mfma_f32_16x16x32_bf16(af[0], wmd[0], fz, 0, 0, 0);
        al = __builtin_amdgcn_mfma_f32_16x16x32_bf16(af[0], wlo[0], fz, 0, 0, 0);
        ah = __builtin_amdgcn_mfma_f32_16x16x32_bf16(af[1], whi[1], ah, 0, 0, 0);
        am = __builtin_amdgcn_mfma_f32_16x16x32_bf16(af[1], wmd[1], am, 0, 0, 0);
        al = __builtin_amdgcn_mfma_f32_16x16x32_bf16(af[1], wlo[1], al, 0, 0, 0);
    };

    auto lif_step = [&](const floatx4& ah, const floatx4& am, const floatx4& al,
                        const float* xb) {
        floatx4 s;
        #pragma unroll
        for (int r = 0; r < 4; ++r) s[r] = (ah[r] + am[r]) + al[r];
        #pragma unroll
        for (int j = 0; j < 7; ++j) {
            floatx4 p = *(const floatx4*)(xb + j * 256 + lane * 4);
            #pragma unroll
            for (int r = 0; r < 4; ++r) s[r] += p[r];
        }
        #pragma unroll
        for (int r = 0; r < 4; ++r) {
            float x    = s[r];
            float vdec = v[r] + 0.1f * ((0.0f - v[r]) + cu[r]);  // DT*TAU_MEM_INV
            float idec = cu[r] - 0.2f * cu[r];                    // DT*TAU_SYN_INV
            bool  spk  = (vdec - 1.0f) > 0.0f;                    // heaviside
            zf[r] = spk ? 1.0f : 0.0f;
            v[r]  = spk ? 0.0f : vdec;                            // V_RESET = 0
            cu[r] = idec + x;
        }
    };

    floatx4 ahA = fz, amA = fz, alA = fz;   // even-t accumulators
    floatx4 ahB = fz, amB = fz, alB = fz;   // odd-t accumulators
    short8 afA[2], afB[2];

    uintx2 bqA = ldbits(0);
    uintx2 bqB = ldbits(1);

    for (int t = 0; t < T_STEPS; t += 2) {
        // ======== even: compute t ========
        if (wq == 0 && t > 0)
            lif_step(ahB, amB, alB, &xbuf[1][0]);   // LIF(t-1), reads xbuf[1]
        expand(bqA, afA);
        if (t + 2 < T_STEPS) bqA = ldbits(t + 2);
        mfma3(afA, ahA, amA, alA);
        if (wq > 0) {
            floatx4 xp;
            #pragma unroll
            for (int r = 0; r < 4; ++r) xp[r] = (ahA[r] + amA[r]) + alA[r];
            *(floatx4*)&xbuf[0][(wq - 1) * 256 + lane * 4] = xp;
        }
        __syncthreads();   // xbuf[0] ready; xbuf[1] reads done

        // ======== odd: compute t+1 ========
        if (wq == 0)
            lif_step(ahA, amA, alA, &xbuf[0][0]);   // LIF(t), reads xbuf[0]
        expand(bqB, afB);
        if (t + 3 < T_STEPS) bqB = ldbits(t + 3);
        mfma3(afB, ahB, amB, alB);
        if (wq > 0) {
            floatx4 xp;
            #pragma unroll
            for (int r = 0; r < 4; ++r) xp[r] = (ahB[r] + amB[r]) + alB[r];
            *(floatx4*)&xbuf[1][(wq - 1) * 256 + lane * 4] = xp;
        }
        __syncthreads();   // xbuf[1] ready; xbuf[0] reads done
    }
    // epilogue: LIF(1023) from B accumulators
    if (wq == 0) {
        lif_step(ahB, amB, alB, &xbuf[1][0]);
        #pragma unroll
        for (int r = 0; r < 4; ++r) {
            const size_t idx = (size_t)(b0 + lq * 4 + r) * F_DIM + gw + mrow;
            out[idx]          = zf[r];
            out[BF + idx]     = v[r];
            out[2 * BF + idx] = cu[r];
        }
    }
}

// ---------------- fallback: R3 fp32-input kernel (verified) ----------------
__global__ __launch_bounds__(256, 1)
void lif_kernel_f32(const float* __restrict__ spikes,
                    const float* __restrict__ W,
                    float* __restrict__ out)
{
    __shared__ unsigned short sAf[16 * ROWP];
    __shared__ float xbuf[2 * 256];

    const int tid  = threadIdx.x;
    const int lane = tid & 63;
    const int w    = tid >> 6;
    const int gh   = w & 1;
    const int kh   = w >> 1;
    const int bt   = blockIdx.x & 15;
    const int gb   = blockIdx.x >> 4;
    const int b0   = bt * 16;
    const int gw   = gb * 32 + gh * 16;
    const int mrow = lane & 15;
    const int kq   = lane >> 4;

    short8 whi[8], wmd[8], wlo[8];
    {
        const float* wp = W + (size_t)(gw + mrow) * F_DIM + kh * 256 + kq * 8;
        #pragma unroll
        for (int ks = 0; ks < 8; ++ks) {
            short8 hi, md, lo;
            #pragma unroll
            for (int j = 0; j < 8; ++j) {
                float f = wp[ks * 32 + j];
                unsigned short h = f2bf_rne(f);
                float r1 = f - bf2f(h);
                unsigned short m = f2bf_rne(r1);
                float r2 = r1 - bf2f(m);
                hi[j] = (short)h;
                md[j] = (short)m;
                lo[j] = (short)f2bf_rne(r2);
            }
            whi[ks] = hi; wmd[ks] = md; wlo[ks] = lo;
        }
    }

    float v[4]  = {0.f, 0.f, 0.f, 0.f};
    float cu[4] = {0.f, 0.f, 0.f, 0.f};
    float zf[4] = {0.f, 0.f, 0.f, 0.f};

    floatx4 ld[8];
    auto issue_loads = [&](int t) {
        const floatx4* sp = (const floatx4*)(spikes + (size_t)t * BF + (size_t)b0 * F_DIM);
        #pragma unroll
        for (int j = 0; j < 8; ++j)
            ld[j] = sp[tid + 256 * j];
    };

    issue_loads(0);
    for (int t = 0; t < T_STEPS; ++t) {
        #pragma unroll
        for (int j = 0; j < 8; ++j) {
            const int q = tid + 256 * j;
            const int row = q >> 7, col4 = q & 127;
            unsigned u0 = __float_as_uint(ld[j][0]);
            unsigned u1 = __float_as_uint(ld[j][1]);
            unsigned u2 = __float_as_uint(ld[j][2]);
            unsigned u3 = __float_as_uint(ld[j][3]);
            uintx2 d;
            d[0] = (u0 >> 16) | (u1 & 0xFFFF0000u);
            d[1] = (u2 >> 16) | (u3 & 0xFFFF0000u);
            *(uintx2*)&sAf[row * ROWP + col4 * 4] = d;
        }
        __syncthreads();
        if (t + 1 < T_STEPS) issue_loads(t + 1);

        floatx4 ah = {0.f, 0.f, 0.f, 0.f};
        floatx4 am = {0.f, 0.f, 0.f, 0.f};
        floatx4 al = {0.f, 0.f, 0.f, 0.f};
        const unsigned short* arow = &sAf[mrow * ROWP + kh * 256 + kq * 8];
        #pragma unroll
        for (int ks = 0; ks < 8; ++ks) {
            short8 a = *(const short8*)(arow + ks * 32);
            ah = __builtin_amdgcn_mfma_f32_16x16x32_bf16(a, whi[ks], ah, 0, 0, 0);
            am = __builtin_amdgcn_mfma_f32_16x16x32_bf16(a, wmd[ks], am, 0, 0, 0);
            al = __builtin_amdgcn_mfma_f32_16x16x32_bf16(a, wlo[ks], al, 0, 0, 0);
        }

        if (kh == 1) {
            floatx4 xp = (ah + am) + al;
            *(floatx4*)&xbuf[gh * 256 + lane * 4] = xp;
        }
        __syncthreads();
        if (kh == 0) {
            floatx4 other = *(const floatx4*)&xbuf[gh * 256 + lane * 4];
            #pragma unroll
            for (int r = 0; r < 4; ++r) {
                float x    = ((ah[r] + am[r]) + al[r]) + other[r];
                float vdec = v[r] + 0.1f * ((0.0f - v[r]) + cu[r]);
                float idec = cu[r] - 0.2f * cu[r];
                bool  spk  = (vdec - 1.0f) > 0.0f;
                zf[r] = spk ? 1.0f : 0.0f;
                v[r]  = spk ? 0.0f : vdec;
                cu[r] = idec + x;
            }
        }
    }

    if (kh == 0) {
        #pragma unroll
        for (int r = 0; r < 4; ++r) {
            const size_t idx = (size_t)(b0 + kq * 4 + r) * F_DIM + gw + mrow;
            out[idx]          = zf[r];
            out[BF + idx]     = v[r];
            out[2 * BF + idx] = cu[r];
        }
    }
}

extern "C" void kernel_launch(void* const* d_in, const int* in_sizes, int n_in,
                              void* d_out, int out_size, void* d_ws, size_t ws_size,
                              hipStream_t stream)
{
    const float* spikes = (const float*)d_in[0];   // [T,B,F] fp32
    const float* W      = (const float*)d_in[1];   // [F,F]   fp32
    float* out          = (float*)d_out;           // [3,B,F] fp32

    const size_t need = (size_t)T_STEPS * B_DIM * (F_DIM / 8);  // 16 MiB bitmask
    if (d_ws != nullptr && ws_size >= need) {
        unsigned* bits = (unsigned*)d_ws;
        pack_kernel<<<dim3(2048), dim3(256), 0, stream>>>(spikes, bits);
        lif_kernel_bits<<<dim3(512), dim3(512), 0, stream>>>(bits, W, out);
    } else {
        lif_kernel_f32<<<dim3(256), dim3(256), 0, stream>>>(spikes, W, out);
    }
}

// Round 6
// 1147.182 us; speedup vs baseline: 1.0662x; 1.0662x over previous
//
#include <hip/hip_runtime.h>
#include <hip/hip_bf16.h>

// LIF fused kernel, Round 9: exact-integer i8 MFMA engine.
//
// R8 post-mortem: VALU-issue-bound (VALUBusy 55.7% = 773 cy/t of 1387;
// MfmaUtil 30% = bf16 MFMA floor 466 cy/t; idle ~15%). Occupancy is not
// the lever; the instruction budget is.
//
// R9: spikes {0,1} are exact in i8; W quantized per OUTPUT ROW to 24-bit
// ints split into 3 signed i8 digits (q = d0*2^16 + d1*2^8 + d2, exact;
// |d0|<=123). 3x mfma_i32_16x16x64_i8 (K=64, 2x bf16 rate) with EXACT i32
// accumulation -> MFMA floor 466->245 cy/t, W frags 48->12 VGPR, and the
// bits->i8 expansion (u = b4+(b4<<7)+(b4<<14)+(b4<<21) & 0x01010101,
// 5 ops/dword) is ~2x cheaper than bits->bf16. Exact integer accumulation
// makes any internal k-slot permutation of the i8 fragment harmless (A and
// B share byte slots). Reconstruction M = acc0*65536 + (acc1<<8 + acc2)
// (int exact, one fma), scaled once by per-row invC in the LIF wave.
// Error <= rowmax/2^23 per element (~1e-8) + fp32 combine noise ~1e-7 --
// same regime as the accepted bf16 3-term split.
//
// Skeleton (grid 512 = 16bt x 32gb, 2 blocks/CU, 8 K-eighth waves,
// ping-pong accs, dbuf xbuf, deferred LIF, 1 barrier/t) identical to R8.
//
// Packed layout: bits[t*4096 + b*16 + wd], bit j (LSB) = spike[t][b][wd*32+j].

typedef __attribute__((ext_vector_type(8))) short short8;   // 8 x bf16
typedef __attribute__((ext_vector_type(4))) float floatx4;
typedef __attribute__((ext_vector_type(2))) unsigned uintx2;
typedef __attribute__((ext_vector_type(4))) int int4v;

#define T_STEPS 1024
#define B_DIM   256
#define F_DIM   512
#define BF      (B_DIM * F_DIM)
#define ROWP    520   // (fallback kernel only)

static __device__ __forceinline__ unsigned short f2bf_rne(float f) {
    unsigned u = __float_as_uint(f);
    return (unsigned short)((u + 0x7FFFu + ((u >> 16) & 1u)) >> 16);
}
static __device__ __forceinline__ float bf2f(unsigned short h) {
    return __uint_as_float(((unsigned)h) << 16);
}

// ---------------- prepass: fp32 {0,1} -> bitmask ----------------
__global__ __launch_bounds__(256)
void pack_kernel(const float* __restrict__ sp, unsigned* __restrict__ bits)
{
    const int lane = threadIdx.x & 63;
    const int wv   = blockIdx.x * 4 + (threadIdx.x >> 6);
    for (int c = wv; c < 65536; c += 2048 * 4) {
        const float* p = sp + (size_t)c * 2048;
        unsigned val = 0;
        #pragma unroll
        for (int r = 0; r < 32; ++r) {
            float x = p[r * 64 + lane];
            unsigned long long m = __ballot(x != 0.0f);
            unsigned sel = (lane & 1) ? (unsigned)(m >> 32) : (unsigned)m;
            if ((lane >> 1) == r) val = sel;
        }
        bits[(size_t)c * 64 + lane] = val;
    }
}

// -------- main kernel: i8 MFMA, register A, 8 K-eighth waves ------------
__global__ __launch_bounds__(512, 4)
void lif_kernel_bits(const unsigned* __restrict__ bits,
                     const float* __restrict__ W,
                     float* __restrict__ out)
{
    __shared__ float xbuf[2][7 * 256];   // dbuf x 7 partial waves x 16x16 tile
    __shared__ float rowmax[8][16];      // setup-only: per-wave row maxima

    const int tid  = threadIdx.x;
    const int lane = tid & 63;
    const int wq   = tid >> 6;          // 0..7: K-eighth, k in [wq*64, wq*64+64)
    const int bt   = blockIdx.x & 15;
    const int gb   = blockIdx.x >> 4;   // 0..31
    const int b0   = bt * 16;
    const int gw   = gb * 16;
    const int mrow = lane & 15;
    const int lq   = lane >> 4;         // 0..3: k-chunk of 16 within the 64

    // ---- W setup (once): rows gw+mrow, k = wq*64 + lq*16 + j, j=0..15
    // Row-scale quantization to 3 signed i8 digit planes (exact 24-bit).
    int4v wi0, wi1, wi2;
    float invC;
    {
        const float* wp = W + (size_t)(gw + mrow) * F_DIM + wq * 64 + lq * 16;
        float wv[16];
        float lm = 0.0f;
        #pragma unroll
        for (int j = 0; j < 16; ++j) {
            wv[j] = wp[j];
            lm = fmaxf(lm, fabsf(wv[j]));
        }
        // max across the 4 k-chunks (lanes with same mrow: xor 16, 32)
        lm = fmaxf(lm, __shfl_xor(lm, 16, 64));
        lm = fmaxf(lm, __shfl_xor(lm, 32, 64));
        if (lane < 16) rowmax[wq][lane] = lm;
        __syncthreads();
        float S = 1e-30f;
        #pragma unroll
        for (int w8 = 0; w8 < 8; ++w8) S = fmaxf(S, rowmax[w8][mrow]);
        __syncthreads();   // rowmax consumed before any later LDS activity
        const float C = 8000000.0f / S;    // |q| <= 8e6 < digit-range limit
        invC = S / 8000000.0f;
        #pragma unroll
        for (int d = 0; d < 4; ++d) {
            unsigned p0 = 0, p1 = 0, p2 = 0;
            #pragma unroll
            for (int jj = 0; jj < 4; ++jj) {
                int q  = __float2int_rn(wv[d * 4 + jj] * C);
                int d2 = (q << 24) >> 24;          // sext low byte
                int r1 = (q - d2) >> 8;            // exact (divisible)
                int d1 = (r1 << 24) >> 24;
                int d0 = (r1 - d1) >> 8;           // |d0| <= 123
                p0 |= (unsigned)(d0 & 0xFF) << (8 * jj);
                p1 |= (unsigned)(d1 & 0xFF) << (8 * jj);
                p2 |= (unsigned)(d2 & 0xFF) << (8 * jj);
            }
            wi0[d] = (int)p0; wi1[d] = (int)p1; wi2[d] = (int)p2;
        }
    }

    // ---- LIF state (wq==0 wave), C-layout: b = b0+lq*4+r, g = gw+mrow
    float v[4]  = {0.f, 0.f, 0.f, 0.f};
    float cu[4] = {0.f, 0.f, 0.f, 0.f};
    float zf[4] = {0.f, 0.f, 0.f, 0.f};

    // bits source: lane's row is b0+mrow; its 64-bit k-slice is dwords
    // wq*2, wq*2+1; its 16-bit sub-slice selected by lq.
    const unsigned* bp = bits + (size_t)(b0 + mrow) * 16 + wq * 2;  // +4096/t

    auto ldbits = [&](int t) -> uintx2 {
        return *(const uintx2*)(bp + (size_t)t * 4096);
    };

    // expand 16 bits -> 16 i8 bytes {0,1} (4 dwords)
    // per dword: u = b4 + (b4<<7) + (b4<<14) + (b4<<21), & 0x01010101
    auto expand = [&](uintx2 bq) -> int4v {
        unsigned h16 = ((lq & 2) ? bq[1] : bq[0]) >> ((lq & 1) * 16);
        int4v a;
        #pragma unroll
        for (int d = 0; d < 4; ++d) {
            unsigned b4 = (h16 >> (4 * d)) & 0xFu;
            unsigned u  = (b4 << 7) + b4;
            u = (b4 << 14) + u;
            u = (b4 << 21) + u;
            a[d] = (int)(u & 0x01010101u);
        }
        return a;
    };

    const int4v iz = {0, 0, 0, 0};

    // 3 exact-int MFMAs + combine to fp32 M = acc0*2^16 + acc1*2^8 + acc2
    auto mfma_combine = [&](int4v aI) -> floatx4 {
        int4v acc0 = __builtin_amdgcn_mfma_i32_16x16x64_i8(aI, wi0, iz, 0, 0, 0);
        int4v acc1 = __builtin_amdgcn_mfma_i32_16x16x64_i8(aI, wi1, iz, 0, 0, 0);
        int4v acc2 = __builtin_amdgcn_mfma_i32_16x16x64_i8(aI, wi2, iz, 0, 0, 0);
        floatx4 M;
        #pragma unroll
        for (int r = 0; r < 4; ++r) {
            int a12 = (acc1[r] << 8) + acc2[r];          // exact int (<2^25)
            M[r] = fmaf((float)acc0[r], 65536.0f, (float)a12);
        }
        return M;
    };

    auto lif_step = [&](const floatx4& Mown, const float* xb) {
        floatx4 s = Mown;
        #pragma unroll
        for (int j = 0; j < 7; ++j) {
            floatx4 p = *(const floatx4*)(xb + j * 256 + lane * 4);
            #pragma unroll
            for (int r = 0; r < 4; ++r) s[r] += p[r];
        }
        #pragma unroll
        for (int r = 0; r < 4; ++r) {
            float x    = s[r] * invC;
            float vdec = v[r] + 0.1f * ((0.0f - v[r]) + cu[r]);  // DT*TAU_MEM_INV
            float idec = cu[r] - 0.2f * cu[r];                    // DT*TAU_SYN_INV
            bool  spk  = (vdec - 1.0f) > 0.0f;                    // heaviside
            zf[r] = spk ? 1.0f : 0.0f;
            v[r]  = spk ? 0.0f : vdec;                            // V_RESET = 0
            cu[r] = idec + x;
        }
    };

    floatx4 MA = {0.f, 0.f, 0.f, 0.f};   // even-t combined partial (wq0)
    floatx4 MB = {0.f, 0.f, 0.f, 0.f};   // odd-t combined partial (wq0)

    uintx2 bqA = ldbits(0);
    uintx2 bqB = ldbits(1);

    for (int t = 0; t < T_STEPS; t += 2) {
        // ======== even: compute t ========
        if (wq == 0 && t > 0)
            lif_step(MB, &xbuf[1][0]);              // LIF(t-1), reads xbuf[1]
        {
            int4v aI = expand(bqA);
            if (t + 2 < T_STEPS) bqA = ldbits(t + 2);
            floatx4 M = mfma_combine(aI);
            if (wq > 0) *(floatx4*)&xbuf[0][(wq - 1) * 256 + lane * 4] = M;
            else        MA = M;
        }
        __syncthreads();   // xbuf[0] ready; xbuf[1] reads done

        // ======== odd: compute t+1 ========
        if (wq == 0)
            lif_step(MA, &xbuf[0][0]);              // LIF(t), reads xbuf[0]
        {
            int4v aI = expand(bqB);
            if (t + 3 < T_STEPS) bqB = ldbits(t + 3);
            floatx4 M = mfma_combine(aI);
            if (wq > 0) *(floatx4*)&xbuf[1][(wq - 1) * 256 + lane * 4] = M;
            else        MB = M;
        }
        __syncthreads();   // xbuf[1] ready; xbuf[0] reads done
    }
    // epilogue: LIF(1023) from odd partials
    if (wq == 0) {
        lif_step(MB, &xbuf[1][0]);
        #pragma unroll
        for (int r = 0; r < 4; ++r) {
            const size_t idx = (size_t)(b0 + lq * 4 + r) * F_DIM + gw + mrow;
            out[idx]          = zf[r];
            out[BF + idx]     = v[r];
            out[2 * BF + idx] = cu[r];
        }
    }
}

// ---------------- fallback: R3 fp32-input kernel (verified) ----------------
__global__ __launch_bounds__(256, 1)
void lif_kernel_f32(const float* __restrict__ spikes,
                    const float* __restrict__ W,
                    float* __restrict__ out)
{
    __shared__ unsigned short sAf[16 * ROWP];
    __shared__ float xbuf[2 * 256];

    const int tid  = threadIdx.x;
    const int lane = tid & 63;
    const int w    = tid >> 6;
    const int gh   = w & 1;
    const int kh   = w >> 1;
    const int bt   = blockIdx.x & 15;
    const int gb   = blockIdx.x >> 4;
    const int b0   = bt * 16;
    const int gw   = gb * 32 + gh * 16;
    const int mrow = lane & 15;
    const int kq   = lane >> 4;

    short8 whi[8], wmd[8], wlo[8];
    {
        const float* wp = W + (size_t)(gw + mrow) * F_DIM + kh * 256 + kq * 8;
        #pragma unroll
        for (int ks = 0; ks < 8; ++ks) {
            short8 hi, md, lo;
            #pragma unroll
            for (int j = 0; j < 8; ++j) {
                float f = wp[ks * 32 + j];
                unsigned short h = f2bf_rne(f);
                float r1 = f - bf2f(h);
                unsigned short m = f2bf_rne(r1);
                float r2 = r1 - bf2f(m);
                hi[j] = (short)h;
                md[j] = (short)m;
                lo[j] = (short)f2bf_rne(r2);
            }
            whi[ks] = hi; wmd[ks] = md; wlo[ks] = lo;
        }
    }

    float v[4]  = {0.f, 0.f, 0.f, 0.f};
    float cu[4] = {0.f, 0.f, 0.f, 0.f};
    float zf[4] = {0.f, 0.f, 0.f, 0.f};

    floatx4 ld[8];
    auto issue_loads = [&](int t) {
        const floatx4* sp = (const floatx4*)(spikes + (size_t)t * BF + (size_t)b0 * F_DIM);
        #pragma unroll
        for (int j = 0; j < 8; ++j)
            ld[j] = sp[tid + 256 * j];
    };

    issue_loads(0);
    for (int t = 0; t < T_STEPS; ++t) {
        #pragma unroll
        for (int j = 0; j < 8; ++j) {
            const int q = tid + 256 * j;
            const int row = q >> 7, col4 = q & 127;
            unsigned u0 = __float_as_uint(ld[j][0]);
            unsigned u1 = __float_as_uint(ld[j][1]);
            unsigned u2 = __float_as_uint(ld[j][2]);
            unsigned u3 = __float_as_uint(ld[j][3]);
            uintx2 d;
            d[0] = (u0 >> 16) | (u1 & 0xFFFF0000u);
            d[1] = (u2 >> 16) | (u3 & 0xFFFF0000u);
            *(uintx2*)&sAf[row * ROWP + col4 * 4] = d;
        }
        __syncthreads();
        if (t + 1 < T_STEPS) issue_loads(t + 1);

        floatx4 ah = {0.f, 0.f, 0.f, 0.f};
        floatx4 am = {0.f, 0.f, 0.f, 0.f};
        floatx4 al = {0.f, 0.f, 0.f, 0.f};
        const unsigned short* arow = &sAf[mrow * ROWP + kh * 256 + kq * 8];
        #pragma unroll
        for (int ks = 0; ks < 8; ++ks) {
            short8 a = *(const short8*)(arow + ks * 32);
            ah = __builtin_amdgcn_mfma_f32_16x16x32_bf16(a, whi[ks], ah, 0, 0, 0);
            am = __builtin_amdgcn_mfma_f32_16x16x32_bf16(a, wmd[ks], am, 0, 0, 0);
            al = __builtin_amdgcn_mfma_f32_16x16x32_bf16(a, wlo[ks], al, 0, 0, 0);
        }

        if (kh == 1) {
            floatx4 xp = (ah + am) + al;
            *(floatx4*)&xbuf[gh * 256 + lane * 4] = xp;
        }
        __syncthreads();
        if (kh == 0) {
            floatx4 other = *(const floatx4*)&xbuf[gh * 256 + lane * 4];
            #pragma unroll
            for (int r = 0; r < 4; ++r) {
                float x    = ((ah[r] + am[r]) + al[r]) + other[r];
                float vdec = v[r] + 0.1f * ((0.0f - v[r]) + cu[r]);
                float idec = cu[r] - 0.2f * cu[r];
                bool  spk  = (vdec - 1.0f) > 0.0f;
                zf[r] = spk ? 1.0f : 0.0f;
                v[r]  = spk ? 0.0f : vdec;
                cu[r] = idec + x;
            }
        }
    }

    if (kh == 0) {
        #pragma unroll
        for (int r = 0; r < 4; ++r) {
            const size_t idx = (size_t)(b0 + kq * 4 + r) * F_DIM + gw + mrow;
            out[idx]          = zf[r];
            out[BF + idx]     = v[r];
            out[2 * BF + idx] = cu[r];
        }
    }
}

extern "C" void kernel_launch(void* const* d_in, const int* in_sizes, int n_in,
                              void* d_out, int out_size, void* d_ws, size_t ws_size,
                              hipStream_t stream)
{
    const float* spikes = (const float*)d_in[0];   // [T,B,F] fp32
    const float* W      = (const float*)d_in[1];   // [F,F]   fp32
    float* out          = (float*)d_out;           // [3,B,F] fp32

    const size_t need = (size_t)T_STEPS * B_DIM * (F_DIM / 8);  // 16 MiB bitmask
    if (d_ws != nullptr && ws_size >= need) {
        unsigned* bits = (unsigned*)d_ws;
        pack_kernel<<<dim3(2048), dim3(256), 0, stream>>>(spikes, bits);
        lif_kernel_bits<<<dim3(512), dim3(512), 0, stream>>>(bits, W, out);
    } else {
        lif_kernel_f32<<<dim3(256), dim3(256), 0, stream>>>(spikes, W, out);
    }
}